// Round 5
// baseline (78.199 us; speedup 1.0000x reference)
//
#include <hip/hip_runtime.h>
#include <math.h>

#define FEAT 2048
#define NBINS 32
#define NROWS 16384
#define NCLS 64
#define SB 1024         // stat blocks (4 per CU)
#define RPB 16          // rows per stat block

typedef __attribute__((ext_vector_type(8))) short short8;
typedef __attribute__((ext_vector_type(4))) float f32x4;

// packed RNE f32x2 -> bf16x2
static __device__ __forceinline__ unsigned int pk2bf(float a, float b) {
    unsigned ua = __float_as_uint(a);
    unsigned ub = __float_as_uint(b);
    ua = (ua + 0x7FFFu + ((ua >> 16) & 1u)) >> 16;
    ub = (ub + 0x7FFFu + ((ub >> 16) & 1u)) & 0xFFFF0000u;
    return ua | ub;
}

// ---------------- K1: pure streaming partial column sums / sumsq ----------------
// grid 1024 x 256. Block b owns rows [b*16, b*16+16). Fully coalesced.
__global__ __launch_bounds__(256) void k1_stats(const float* __restrict__ x,
                                                float* __restrict__ pS1,
                                                float* __restrict__ pS2) {
    const int b = blockIdx.x, t = threadIdx.x;
    const float4* xb = reinterpret_cast<const float4*>(x) + (size_t)b * RPB * (FEAT / 4);
    float4 s1a = make_float4(0.f,0.f,0.f,0.f), s1b = make_float4(0.f,0.f,0.f,0.f);
    float4 s2a = make_float4(0.f,0.f,0.f,0.f), s2b = make_float4(0.f,0.f,0.f,0.f);
    #pragma unroll
    for (int r = 0; r < RPB; ++r) {
        const float4 va = xb[(size_t)r * (FEAT / 4) + t];
        const float4 vb = xb[(size_t)r * (FEAT / 4) + t + 256];
        s1a.x += va.x; s1a.y += va.y; s1a.z += va.z; s1a.w += va.w;
        s2a.x += va.x * va.x; s2a.y += va.y * va.y; s2a.z += va.z * va.z; s2a.w += va.w * va.w;
        s1b.x += vb.x; s1b.y += vb.y; s1b.z += vb.z; s1b.w += vb.w;
        s2b.x += vb.x * vb.x; s2b.y += vb.y * vb.y; s2b.z += vb.z * vb.z; s2b.w += vb.w * vb.w;
    }
    float4* o1 = reinterpret_cast<float4*>(pS1 + (size_t)b * FEAT);
    float4* o2 = reinterpret_cast<float4*>(pS2 + (size_t)b * FEAT);
    o1[t] = s1a; o1[t + 256] = s1b;
    o2[t] = s2a; o2[t + 256] = s2b;
}

// ---------------- K2: finalize stats (fp64) -> ms, isig ----------------
// grid 256 x 256. Block owns 8 columns; threads = 32 segs x 8 cols.
// Per-wave loads: 8 rows x 32B aligned chunks (coalesced). Fixed-order sums.
__global__ __launch_bounds__(256) void k2_stats(const float* __restrict__ pS1,
                                                const float* __restrict__ pS2,
                                                float* __restrict__ ms,
                                                float* __restrict__ isig_g) {
    __shared__ double sh1[32][8];
    __shared__ double sh2[32][8];
    const int t = threadIdx.x;
    const int ci = t & 7, s = t >> 3;
    const int c = blockIdx.x * 8 + ci;
    double S1 = 0.0, S2 = 0.0;
    #pragma unroll 4
    for (int j = 0; j < 32; ++j) {
        const int k = s * 32 + j;
        S1 += (double)pS1[(size_t)k * FEAT + c];
        S2 += (double)pS2[(size_t)k * FEAT + c];
    }
    sh1[s][ci] = S1; sh2[s][ci] = S2;
    __syncthreads();
    if (t < 8) {
        double s1 = 0.0, s2 = 0.0;
        #pragma unroll
        for (int q = 0; q < 32; ++q) { s1 += sh1[q][t]; s2 += sh2[q][t]; }
        const int cc = blockIdx.x * 8 + t;
        const double n = (double)NROWS;
        const double bm = s1 / n;
        const double bv = (s2 - s1 * s1 / n) / (n - 1.0);
        const double tot = 1e-4 + n;
        const double mean = bm * (n / tot);
        const double m2 = 1e-4 + bv * n + bm * bm * (1e-4 * n / tot);
        const double var = m2 / tot;
        const double isig = 1.0 / sqrt(var + 1e-8);
        ms[cc] = (float)(mean * isig);
        isig_g[cc] = (float)isig;
    }
}

// ---------------- K2q: build Q in B-fragment order (bf16) ----------------
// grid 64 x 256. Block covers 32 k-columns == one (ch,ks) group.
__global__ __launch_bounds__(256) void k2q_frag(const float* __restrict__ isig_g,
                                                const float* __restrict__ P,
                                                unsigned int* __restrict__ QTf) {
    __shared__ float isig_sh[32];
    const int t = threadIdx.x;
    if (t < 32) isig_sh[t] = isig_g[blockIdx.x * 32 + t];
    __syncthreads();
    const int nb = t >> 7;
    const int lane = (t & 127) >> 1;
    const int half = t & 1;
    const int lrow = lane & 15, lk = lane >> 4;
    const int bin = nb * 16 + lrow;
    const int ccl = lk * 8 + half * 4;
    const int cc = blockIdx.x * 32 + ccl;
    unsigned int w0 = pk2bf(P[(size_t)cc * NBINS + bin] * isig_sh[ccl],
                            P[(size_t)(cc + 1) * NBINS + bin] * isig_sh[ccl + 1]);
    unsigned int w1 = pk2bf(P[(size_t)(cc + 2) * NBINS + bin] * isig_sh[ccl + 2],
                            P[(size_t)(cc + 3) * NBINS + bin] * isig_sh[ccl + 3]);
    const int ch = blockIdx.x >> 2, ks = blockIdx.x & 3;
    char* dst = reinterpret_cast<char*>(QTf) +
                (size_t)(((nb * 16 + ch) * 4 + ks) * 1024 + lane * 16 + half * 8);
    uint2 pk; pk.x = w0; pk.y = w1;
    *reinterpret_cast<uint2*>(dst) = pk;
}

// ---------------- K2b: offs[b] = sum_f ms[f] * P[f][b] ----------------
__global__ __launch_bounds__(256) void k2b_offset(const float* __restrict__ ms,
                                                  const float* __restrict__ P,
                                                  float* __restrict__ offs) {
    __shared__ double sh[256];
    const int b = blockIdx.x, t = threadIdx.x;
    double s = 0.0;
    for (int f = t; f < FEAT; f += 256) s += (double)ms[f] * (double)P[(size_t)f * NBINS + b];
    sh[t] = s;
    __syncthreads();
    for (int st = 128; st > 0; st >>= 1) {
        if (t < st) sh[t] += sh[t + st];
        __syncthreads();
    }
    if (t == 0) offs[b] = (float)sh[0];
}

// ---------------- K3: MFMA projection, f32 in / reg cvt, 2-way K-split --------
// grid 256 x 512 (8 waves). Wave w: rows bid*64 + (w&3)*16 .. +16,
// K-half (w>>2): K in [kh*1024, kh*1024+1024). One LDS reduction + barrier,
// then the validated ballot-hash epilogue on waves kh==0.
__global__ __launch_bounds__(512) void k3_mfma(const float* __restrict__ x,
                                               const unsigned int* __restrict__ QTf,
                                               const float* __restrict__ offs,
                                               unsigned int* __restrict__ hout) {
    __shared__ f32x4 red[4][2][64];   // 8KB
    const int t = threadIdx.x;
    const int w = t >> 6, l = t & 63;
    const int rw = w & 3, kh = w >> 2;
    const int lrow = l & 15, lk = l >> 4;
    const int bid = blockIdx.x;

    const float* ax = x + (size_t)(bid * 64 + rw * 16 + lrow) * FEAT + kh * 1024 + lk * 8;
    const short8* b0p = reinterpret_cast<const short8*>(QTf) + l + kh * 2048;
    const short8* b1p = b0p + 4096;

    f32x4 acc0 = {0.f, 0.f, 0.f, 0.f};
    f32x4 acc1 = {0.f, 0.f, 0.f, 0.f};

    #pragma unroll 8
    for (int ss = 0; ss < 32; ++ss) {
        const float4 va = *reinterpret_cast<const float4*>(ax + ss * 32);
        const float4 vb = *reinterpret_cast<const float4*>(ax + ss * 32 + 4);
        uint4 ap;
        ap.x = pk2bf(va.x, va.y); ap.y = pk2bf(va.z, va.w);
        ap.z = pk2bf(vb.x, vb.y); ap.w = pk2bf(vb.z, vb.w);
        const short8 a  = __builtin_bit_cast(short8, ap);
        const short8 b0 = b0p[ss * 64];
        const short8 b1 = b1p[ss * 64];
        acc0 = __builtin_amdgcn_mfma_f32_16x16x32_bf16(a, b0, acc0, 0, 0, 0);
        acc1 = __builtin_amdgcn_mfma_f32_16x16x32_bf16(a, b1, acc1, 0, 0, 0);
    }

    if (kh) { red[rw][0][l] = acc0; red[rw][1][l] = acc1; }
    __syncthreads();
    if (!kh) {
        const f32x4 r0 = red[rw][0][l];
        const f32x4 r1 = red[rw][1][l];
        acc0 += r0;
        acc1 += r1;
        const float o0 = offs[lrow];
        const float o1 = offs[16 + lrow];
        #pragma unroll
        for (int r = 0; r < 4; ++r) {
            const unsigned long long m0 = __ballot(acc0[r] > o0);
            const unsigned long long m1 = __ballot(acc1[r] > o1);
            if (lrow == 0) {
                const unsigned int h =
                    (unsigned int)((m0 >> (16 * lk)) & 0xFFFFull) |
                    ((unsigned int)((m1 >> (16 * lk)) & 0xFFFFull) << 16);
                const int irow = rw * 16 + lk * 4 + r;      // == i & 63 (class)
                hout[(size_t)irow * 256 + bid] = h;         // class-major
            }
        }
    }
}

// ---------------- K4: per-class prefix occurrence count -> reward ----------------
__global__ __launch_bounds__(256) void k4_count(const unsigned int* __restrict__ hcls,
                                                float* __restrict__ out) {
    __shared__ unsigned int hh[256];
    const int c = blockIdx.x, t = threadIdx.x;
    hh[t] = hcls[(size_t)c * 256 + t];
    __syncthreads();
    const unsigned int mine = hh[t];
    int cnt = 1;
    for (int j = 0; j < 256; ++j) {
        cnt += (j < t && hh[j] == mine) ? 1 : 0;
    }
    out[(size_t)t * NCLS + c] = 1.0f / sqrtf((float)cnt);
}

extern "C" void kernel_launch(void* const* d_in, const int* in_sizes, int n_in,
                              void* d_out, int out_size, void* d_ws, size_t ws_size,
                              hipStream_t stream) {
    const float* x = (const float*)d_in[0];   // 64*256*2048 f32
    const float* P = (const float*)d_in[1];   // 2048*32 f32
    float* out = (float*)d_out;               // 16384 f32
    char* ws = (char*)d_ws;

    float* pS1 = (float*)(ws);                                   // 8MB
    float* pS2 = (float*)(ws + (size_t)SB * FEAT * 4);           // 8MB
    float* ms  = (float*)(ws + (size_t)16 * 1024 * 1024);        // 8KB
    float* isig = ms + FEAT;                                     // 8KB
    float* offsB = isig + FEAT;                                  // 128B
    unsigned int* QTf = (unsigned int*)(ws + (size_t)17 * 1024 * 1024); // 128KB
    unsigned int* h   = (unsigned int*)(ws + (size_t)18 * 1024 * 1024); // 64KB

    k1_stats<<<SB, 256, 0, stream>>>(x, pS1, pS2);
    k2_stats<<<256, 256, 0, stream>>>(pS1, pS2, ms, isig);
    k2q_frag<<<64, 256, 0, stream>>>(isig, P, QTf);
    k2b_offset<<<32, 256, 0, stream>>>(ms, P, offsB);
    k3_mfma<<<256, 512, 0, stream>>>(x, QTf, offsB, h);
    k4_count<<<NCLS, 256, 0, stream>>>(h, out);
}

// Round 6
// 70.395 us; speedup vs baseline: 1.1109x; 1.1109x over previous
//
#include <hip/hip_runtime.h>
#include <math.h>

#define FEAT 2048
#define NBINS 32
#define NROWS 16384
#define NCLS 64
#define SB 1024         // stat blocks (4 per CU)
#define RPB 16          // rows per stat block

typedef __attribute__((ext_vector_type(8))) short short8;
typedef __attribute__((ext_vector_type(4))) float f32x4;

// packed RNE f32x2 -> bf16x2
static __device__ __forceinline__ unsigned int pk2bf(float a, float b) {
    unsigned ua = __float_as_uint(a);
    unsigned ub = __float_as_uint(b);
    ua = (ua + 0x7FFFu + ((ua >> 16) & 1u)) >> 16;
    ub = (ub + 0x7FFFu + ((ub >> 16) & 1u)) & 0xFFFF0000u;
    return ua | ub;
}

// ---------------- K1: pure streaming partial column sums / sumsq ----------------
// grid 1024 x 256. Block b owns rows [b*16, b*16+16). Fully coalesced.
__global__ __launch_bounds__(256) void k1_stats(const float* __restrict__ x,
                                                float* __restrict__ pS1,
                                                float* __restrict__ pS2) {
    const int b = blockIdx.x, t = threadIdx.x;
    const float4* xb = reinterpret_cast<const float4*>(x) + (size_t)b * RPB * (FEAT / 4);
    float4 s1a = make_float4(0.f,0.f,0.f,0.f), s1b = make_float4(0.f,0.f,0.f,0.f);
    float4 s2a = make_float4(0.f,0.f,0.f,0.f), s2b = make_float4(0.f,0.f,0.f,0.f);
    #pragma unroll
    for (int r = 0; r < RPB; ++r) {
        const float4 va = xb[(size_t)r * (FEAT / 4) + t];
        const float4 vb = xb[(size_t)r * (FEAT / 4) + t + 256];
        s1a.x += va.x; s1a.y += va.y; s1a.z += va.z; s1a.w += va.w;
        s2a.x += va.x * va.x; s2a.y += va.y * va.y; s2a.z += va.z * va.z; s2a.w += va.w * va.w;
        s1b.x += vb.x; s1b.y += vb.y; s1b.z += vb.z; s1b.w += vb.w;
        s2b.x += vb.x * vb.x; s2b.y += vb.y * vb.y; s2b.z += vb.z * vb.z; s2b.w += vb.w * vb.w;
    }
    float4* o1 = reinterpret_cast<float4*>(pS1 + (size_t)b * FEAT);
    float4* o2 = reinterpret_cast<float4*>(pS2 + (size_t)b * FEAT);
    o1[t] = s1a; o1[t + 256] = s1b;
    o2[t] = s2a; o2[t + 256] = s2b;
}

// ---------------- K2: finalize stats (fp64) -> ms, isig ----------------
// grid 256 x 256. Block owns 8 columns; threads = 32 segs x 8 cols.
__global__ __launch_bounds__(256) void k2_stats(const float* __restrict__ pS1,
                                                const float* __restrict__ pS2,
                                                float* __restrict__ ms,
                                                float* __restrict__ isig_g) {
    __shared__ double sh1[32][8];
    __shared__ double sh2[32][8];
    const int t = threadIdx.x;
    const int ci = t & 7, s = t >> 3;
    const int c = blockIdx.x * 8 + ci;
    double S1 = 0.0, S2 = 0.0;
    #pragma unroll 4
    for (int j = 0; j < 32; ++j) {
        const int k = s * 32 + j;
        S1 += (double)pS1[(size_t)k * FEAT + c];
        S2 += (double)pS2[(size_t)k * FEAT + c];
    }
    sh1[s][ci] = S1; sh2[s][ci] = S2;
    __syncthreads();
    if (t < 8) {
        double s1 = 0.0, s2 = 0.0;
        #pragma unroll
        for (int q = 0; q < 32; ++q) { s1 += sh1[q][t]; s2 += sh2[q][t]; }
        const int cc = blockIdx.x * 8 + t;
        const double n = (double)NROWS;
        const double bm = s1 / n;
        const double bv = (s2 - s1 * s1 / n) / (n - 1.0);
        const double tot = 1e-4 + n;
        const double mean = bm * (n / tot);
        const double m2 = 1e-4 + bv * n + bm * bm * (1e-4 * n / tot);
        const double var = m2 / tot;
        const double isig = 1.0 / sqrt(var + 1e-8);
        ms[cc] = (float)(mean * isig);
        isig_g[cc] = (float)isig;
    }
}

// ---------------- K2m: merged Q-fragment build (blocks 0..63) + offs (64..95) --
__global__ __launch_bounds__(256) void k2_misc(const float* __restrict__ isig_g,
                                               const float* __restrict__ ms,
                                               const float* __restrict__ P,
                                               unsigned int* __restrict__ QTf,
                                               float* __restrict__ offs) {
    const int t = threadIdx.x;
    if (blockIdx.x < 64) {
        __shared__ float isig_sh[32];
        if (t < 32) isig_sh[t] = isig_g[blockIdx.x * 32 + t];
        __syncthreads();
        const int nb = t >> 7;
        const int lane = (t & 127) >> 1;
        const int half = t & 1;
        const int lrow = lane & 15, lk = lane >> 4;
        const int bin = nb * 16 + lrow;
        const int ccl = lk * 8 + half * 4;
        const int cc = blockIdx.x * 32 + ccl;
        unsigned int w0 = pk2bf(P[(size_t)cc * NBINS + bin] * isig_sh[ccl],
                                P[(size_t)(cc + 1) * NBINS + bin] * isig_sh[ccl + 1]);
        unsigned int w1 = pk2bf(P[(size_t)(cc + 2) * NBINS + bin] * isig_sh[ccl + 2],
                                P[(size_t)(cc + 3) * NBINS + bin] * isig_sh[ccl + 3]);
        const int ch = blockIdx.x >> 2, ks = blockIdx.x & 3;
        char* dst = reinterpret_cast<char*>(QTf) +
                    (size_t)(((nb * 16 + ch) * 4 + ks) * 1024 + lane * 16 + half * 8);
        uint2 pk; pk.x = w0; pk.y = w1;
        *reinterpret_cast<uint2*>(dst) = pk;
    } else {
        __shared__ double sh[256];
        const int b = blockIdx.x - 64;
        double s = 0.0;
        for (int f = t; f < FEAT; f += 256) s += (double)ms[f] * (double)P[(size_t)f * NBINS + b];
        sh[t] = s;
        __syncthreads();
        for (int st = 128; st > 0; st >>= 1) {
            if (t < st) sh[t] += sh[t + st];
            __syncthreads();
        }
        if (t == 0) offs[b] = (float)sh[0];
    }
}

// ---------------- K3: MFMA projection, f32 in / reg cvt, 8-stage prefetch -----
// grid 256 x 256 (4 waves). Wave w: rows bid*64 + w*16 .. +16, all 32 bins.
// Explicit 8-deep register pipeline (static stage indices): 32 loads in flight
// per wave covers global latency at 1 wave/SIMD. No LDS, no barriers.
__global__ __launch_bounds__(256, 1) void k3_mfma(const float* __restrict__ x,
                                                  const unsigned int* __restrict__ QTf,
                                                  const float* __restrict__ offs,
                                                  unsigned int* __restrict__ hout) {
    const int t = threadIdx.x;
    const int w = t >> 6, l = t & 63;
    const int lrow = l & 15, lk = l >> 4;
    const int bid = blockIdx.x;

    const float* ax = x + (size_t)(bid * 64 + w * 16 + lrow) * FEAT + lk * 8;
    const short8* b0p = reinterpret_cast<const short8*>(QTf) + l;
    const short8* b1p = b0p + 4096;

    f32x4 acc0 = {0.f, 0.f, 0.f, 0.f};
    f32x4 acc1 = {0.f, 0.f, 0.f, 0.f};

    float4 va[8], vb[8];
    short8 b0s[8], b1s[8];

    // prologue: fill all 8 stages (ss = 0..7)
    #pragma unroll
    for (int p = 0; p < 8; ++p) {
        va[p] = *reinterpret_cast<const float4*>(ax + p * 32);
        vb[p] = *reinterpret_cast<const float4*>(ax + p * 32 + 4);
        b0s[p] = b0p[p * 64];
        b1s[p] = b1p[p * 64];
    }

    const float* axg = ax;
    const short8* b0g = b0p;
    const short8* b1g = b1p;
    #pragma unroll 1
    for (int g = 0; g < 7; ++g) {
        #pragma unroll
        for (int s2 = 0; s2 < 8; ++s2) {
            uint4 ap;
            ap.x = pk2bf(va[s2].x, va[s2].y); ap.y = pk2bf(va[s2].z, va[s2].w);
            ap.z = pk2bf(vb[s2].x, vb[s2].y); ap.w = pk2bf(vb[s2].z, vb[s2].w);
            const short8 a = __builtin_bit_cast(short8, ap);
            acc0 = __builtin_amdgcn_mfma_f32_16x16x32_bf16(a, b0s[s2], acc0, 0, 0, 0);
            acc1 = __builtin_amdgcn_mfma_f32_16x16x32_bf16(a, b1s[s2], acc1, 0, 0, 0);
            // refill stage s2 with k-step (g+1)*8 + s2
            va[s2] = *reinterpret_cast<const float4*>(axg + (8 + s2) * 32);
            vb[s2] = *reinterpret_cast<const float4*>(axg + (8 + s2) * 32 + 4);
            b0s[s2] = b0g[(8 + s2) * 64];
            b1s[s2] = b1g[(8 + s2) * 64];
        }
        axg += 256; b0g += 512; b1g += 512;
    }
    // final group: consume stages, no refill
    #pragma unroll
    for (int s2 = 0; s2 < 8; ++s2) {
        uint4 ap;
        ap.x = pk2bf(va[s2].x, va[s2].y); ap.y = pk2bf(va[s2].z, va[s2].w);
        ap.z = pk2bf(vb[s2].x, vb[s2].y); ap.w = pk2bf(vb[s2].z, vb[s2].w);
        const short8 a = __builtin_bit_cast(short8, ap);
        acc0 = __builtin_amdgcn_mfma_f32_16x16x32_bf16(a, b0s[s2], acc0, 0, 0, 0);
        acc1 = __builtin_amdgcn_mfma_f32_16x16x32_bf16(a, b1s[s2], acc1, 0, 0, 0);
    }

    const float o0 = offs[lrow];
    const float o1 = offs[16 + lrow];
    #pragma unroll
    for (int r = 0; r < 4; ++r) {
        const unsigned long long m0 = __ballot(acc0[r] > o0);
        const unsigned long long m1 = __ballot(acc1[r] > o1);
        if (lrow == 0) {
            const unsigned int h =
                (unsigned int)((m0 >> (16 * lk)) & 0xFFFFull) |
                ((unsigned int)((m1 >> (16 * lk)) & 0xFFFFull) << 16);
            const int irow = w * 16 + lk * 4 + r;       // == i & 63 (class)
            hout[(size_t)irow * 256 + bid] = h;         // class-major
        }
    }
}

// ---------------- K4: per-class prefix occurrence count -> reward ----------------
__global__ __launch_bounds__(256) void k4_count(const unsigned int* __restrict__ hcls,
                                                float* __restrict__ out) {
    __shared__ unsigned int hh[256];
    const int c = blockIdx.x, t = threadIdx.x;
    hh[t] = hcls[(size_t)c * 256 + t];
    __syncthreads();
    const unsigned int mine = hh[t];
    int cnt = 1;
    for (int j = 0; j < 256; ++j) {
        cnt += (j < t && hh[j] == mine) ? 1 : 0;
    }
    out[(size_t)t * NCLS + c] = 1.0f / sqrtf((float)cnt);
}

extern "C" void kernel_launch(void* const* d_in, const int* in_sizes, int n_in,
                              void* d_out, int out_size, void* d_ws, size_t ws_size,
                              hipStream_t stream) {
    const float* x = (const float*)d_in[0];   // 64*256*2048 f32
    const float* P = (const float*)d_in[1];   // 2048*32 f32
    float* out = (float*)d_out;               // 16384 f32
    char* ws = (char*)d_ws;

    float* pS1 = (float*)(ws);                                   // 8MB
    float* pS2 = (float*)(ws + (size_t)SB * FEAT * 4);           // 8MB
    float* ms  = (float*)(ws + (size_t)16 * 1024 * 1024);        // 8KB
    float* isig = ms + FEAT;                                     // 8KB
    float* offsB = isig + FEAT;                                  // 128B
    unsigned int* QTf = (unsigned int*)(ws + (size_t)17 * 1024 * 1024); // 128KB
    unsigned int* h   = (unsigned int*)(ws + (size_t)18 * 1024 * 1024); // 64KB

    k1_stats<<<SB, 256, 0, stream>>>(x, pS1, pS2);
    k2_stats<<<256, 256, 0, stream>>>(pS1, pS2, ms, isig);
    k2_misc<<<96, 256, 0, stream>>>(isig, ms, P, QTf, offsB);
    k3_mfma<<<256, 256, 0, stream>>>(x, QTf, offsB, h);
    k4_count<<<NCLS, 256, 0, stream>>>(h, out);
}